// Round 1
// baseline (780.464 us; speedup 1.0000x reference)
//
#include <hip/hip_runtime.h>

#define NN 100000
#define NE 1600000
#define SD 128
#define HD 32

// ---------- degree / normalization ----------
__global__ void k_deg(const int* __restrict__ dst, float* __restrict__ deg) {
    int i = blockIdx.x * blockDim.x + threadIdx.x;   // exact: NE/256
    atomicAdd(&deg[dst[i]], 1.0f);
}

__global__ void k_dinv(float* __restrict__ deg) {
    int i = blockIdx.x * blockDim.x + threadIdx.x;
    if (i < NN) deg[i] = rsqrtf(deg[i] + 1.0f);      // +1 self-loop
}

// ---------- h = x @ W1  (N x 128 @ 128 x 32), 8 nodes/block ----------
__global__ void k_mm128(const float* __restrict__ x, const float* __restrict__ W,
                        float* __restrict__ h) {
    __shared__ float Wls[SD * HD];   // 16 KB
    __shared__ float xls[8][SD];     // 4 KB
    int tid = threadIdx.x;
    for (int i = tid; i < SD * HD; i += 256) Wls[i] = W[i];
    int nb = blockIdx.x * 8;
    for (int i = tid; i < 8 * SD; i += 256) {
        int ln = i >> 7, k = i & 127;
        int n = nb + ln;
        xls[ln][k] = (n < NN) ? x[(size_t)n * SD + k] : 0.f;
    }
    __syncthreads();
    int ln = tid >> 5, j = tid & 31;
    int n = nb + ln;
    if (n < NN) {
        float acc = 0.f;
#pragma unroll
        for (int k = 0; k < SD; ++k) acc = fmaf(xls[ln][k], Wls[k * HD + j], acc);
        h[(size_t)n * HD + j] = acc;
    }
}

// ---------- hout = hin @ W  (32 x 32), 8 nodes/block ----------
__global__ void k_mm32(const float* __restrict__ hin, const float* __restrict__ W,
                       float* __restrict__ hout) {
    __shared__ float Wls[HD * HD];
    __shared__ float hls[8][HD];
    int tid = threadIdx.x;
    for (int i = tid; i < HD * HD; i += 256) Wls[i] = W[i];
    int nb = blockIdx.x * 8;
    for (int i = tid; i < 8 * HD; i += 256) {
        int ln = i >> 5, k = i & 31;
        int n = nb + ln;
        hls[ln][k] = (n < NN) ? hin[(size_t)n * HD + k] : 0.f;
    }
    __syncthreads();
    int ln = tid >> 5, j = tid & 31;
    int n = nb + ln;
    if (n < NN) {
        float acc = 0.f;
#pragma unroll
        for (int k = 0; k < HD; ++k) acc = fmaf(hls[ln][k], Wls[k * HD + j], acc);
        hout[(size_t)n * HD + j] = acc;
    }
}

// ---------- edge scatter: agg[dst] += h[src] * norm, 32 lanes = 32 features ----------
__global__ void k_scatter(const int* __restrict__ src, const int* __restrict__ dst,
                          const float* __restrict__ dinv, const float* __restrict__ h,
                          float* __restrict__ agg) {
    int gid = blockIdx.x * blockDim.x + threadIdx.x;  // exact: NE*32/256
    int e = gid >> 5, j = gid & 31;
    int s = src[e], d = dst[e];
    float norm = dinv[s] * dinv[d];
    atomicAdd(&agg[(size_t)d * HD + j], h[(size_t)s * HD + j] * norm);
}

// ---------- finalize: out = agg + h*self_norm + b ----------
__global__ void k_fin(const float* __restrict__ agg, const float* __restrict__ h,
                      const float* __restrict__ dinv, const float* __restrict__ b,
                      float* __restrict__ out) {
    int gid = blockIdx.x * blockDim.x + threadIdx.x;  // exact: NN*32/256
    int n = gid >> 5, j = gid & 31;
    float dv = dinv[n];
    out[gid] = agg[gid] + h[gid] * dv * dv + b[j];
}

// ---------- heads: smu = relu(h2).W2 ; sstd = h2.Ws  (32 lanes/node, shfl reduce) ----------
__global__ void k_heads(const float* __restrict__ h2, const float* __restrict__ W2,
                        const float* __restrict__ Wsd, float* __restrict__ smu,
                        float* __restrict__ sstd) {
    int gid = blockIdx.x * blockDim.x + threadIdx.x;  // exact: NN*32/256
    int n = gid >> 5, j = gid & 31;
    float v = h2[gid];
    float a = fmaxf(v, 0.f) * W2[j];
    float b = v * Wsd[j];
#pragma unroll
    for (int off = 16; off > 0; off >>= 1) {
        a += __shfl_xor(a, off, 32);
        b += __shfl_xor(b, off, 32);
    }
    if (j == 0) { smu[n] = a; sstd[n] = b; }
}

// ---------- scalar edge scatter for mu/std ----------
__global__ void k_escal(const int* __restrict__ src, const int* __restrict__ dst,
                        const float* __restrict__ dinv, const float* __restrict__ smu,
                        const float* __restrict__ sstd, float* __restrict__ amu,
                        float* __restrict__ astd) {
    int e = blockIdx.x * blockDim.x + threadIdx.x;    // exact: NE/256
    int s = src[e], d = dst[e];
    float norm = dinv[s] * dinv[d];
    atomicAdd(&amu[d], smu[s] * norm);
    atomicAdd(&astd[d], sstd[s] * norm);
}

// ---------- combine + write outputs ----------
__global__ void k_out(const float* __restrict__ amu, const float* __restrict__ astd,
                      const float* __restrict__ smu, const float* __restrict__ sstd,
                      const float* __restrict__ dinv, const float* __restrict__ b2,
                      const float* __restrict__ bs, float* __restrict__ out) {
    int n = blockIdx.x * blockDim.x + threadIdx.x;
    if (n < NN) {
        float dv = dinv[n];
        float sn = dv * dv;
        out[n]      = amu[n]  + smu[n]  * sn + b2[0];
        out[NN + n] = astd[n] + sstd[n] * sn + bs[0];
    }
}

extern "C" void kernel_launch(void* const* d_in, const int* in_sizes, int n_in,
                              void* d_out, int out_size, void* d_ws, size_t ws_size,
                              hipStream_t stream) {
    const float* x   = (const float*)d_in[0];
    const int*   ei  = (const int*)d_in[1];
    const int*   src = ei;
    const int*   dst = ei + NE;
    const float* W1  = (const float*)d_in[2];
    const float* b1  = (const float*)d_in[3];
    const float* Wh  = (const float*)d_in[4];
    const float* bh  = (const float*)d_in[5];
    const float* W2  = (const float*)d_in[6];
    const float* b2  = (const float*)d_in[7];
    const float* Wsp = (const float*)d_in[8];
    const float* bs  = (const float*)d_in[9];
    float* out = (float*)d_out;

    // workspace layout (floats): dinv[N] | h[N*32] | agg[N*32] | hc[N*32] |
    //                            smu[N] | sstd[N] | amu[N] | astd[N]   ~= 40.4 MB
    float* f    = (float*)d_ws;
    float* dinv = f;
    float* h    = dinv + NN;
    float* agg  = h   + (size_t)NN * HD;
    float* hc   = agg + (size_t)NN * HD;
    float* smu  = hc  + (size_t)NN * HD;
    float* sstd = smu + NN;
    float* amu  = sstd + NN;
    float* astd = amu + NN;

    // normalization
    hipMemsetAsync(dinv, 0, NN * sizeof(float), stream);
    k_deg<<<NE / 256, 256, 0, stream>>>(dst, dinv);
    k_dinv<<<(NN + 255) / 256, 256, 0, stream>>>(dinv);

    // conv1: h = x@W1 ; hc = agg(h) + h*self + b1
    k_mm128<<<(NN + 7) / 8, 256, 0, stream>>>(x, W1, h);
    hipMemsetAsync(agg, 0, (size_t)NN * HD * sizeof(float), stream);
    k_scatter<<<(size_t)NE * 32 / 256, 256, 0, stream>>>(src, dst, dinv, h, agg);
    k_fin<<<NN * 32 / 256, 256, 0, stream>>>(agg, h, dinv, b1, hc);

    // conv2: h = hc@Wh ; hc = agg(h) + h*self + bh
    k_mm32<<<(NN + 7) / 8, 256, 0, stream>>>(hc, Wh, h);
    hipMemsetAsync(agg, 0, (size_t)NN * HD * sizeof(float), stream);
    k_scatter<<<(size_t)NE * 32 / 256, 256, 0, stream>>>(src, dst, dinv, h, agg);
    k_fin<<<NN * 32 / 256, 256, 0, stream>>>(agg, h, dinv, bh, hc);

    // heads (out-dim 1, fused mu+std)
    k_heads<<<NN * 32 / 256, 256, 0, stream>>>(hc, W2, Wsp, smu, sstd);
    hipMemsetAsync(amu, 0, 2 * NN * sizeof(float), stream);  // amu & astd adjacent
    k_escal<<<NE / 256, 256, 0, stream>>>(src, dst, dinv, smu, sstd, amu, astd);
    k_out<<<(NN + 255) / 256, 256, 0, stream>>>(amu, astd, smu, sstd, dinv, b2, bs, out);
}

// Round 2
// 540.722 us; speedup vs baseline: 1.4434x; 1.4434x over previous
//
#include <hip/hip_runtime.h>

#define NN 100000
#define NE 1600000
#define SD 128
#define HD 32
#define NV4 25000      // NN/4 (exact)
#define NSB 98         // ceil(NV4/256)

// ---------- CSR build ----------
__global__ __launch_bounds__(256) void k_count(const int* __restrict__ dst,
                                               unsigned* __restrict__ cnt) {
    int e = blockIdx.x * 256 + threadIdx.x;          // exact NE/256
    atomicAdd(&cnt[dst[e]], 1u);
}

__global__ __launch_bounds__(256) void k_scanA(const uint4* __restrict__ cnt4,
                                               unsigned* __restrict__ bsum) {
    __shared__ unsigned ts[256];
    int tid = threadIdx.x;
    int f = blockIdx.x * 256 + tid;
    unsigned s = 0;
    if (f < NV4) { uint4 v = cnt4[f]; s = v.x + v.y + v.z + v.w; }
    ts[tid] = s; __syncthreads();
    for (int off = 128; off > 0; off >>= 1) {
        if (tid < off) ts[tid] += ts[tid + off];
        __syncthreads();
    }
    if (tid == 0) bsum[blockIdx.x] = ts[0];
}

__global__ __launch_bounds__(128) void k_scanB(unsigned* __restrict__ bsum,
                                               unsigned* __restrict__ rowptr) {
    __shared__ unsigned s[128];
    int tid = threadIdx.x;
    unsigned v = (tid < NSB) ? bsum[tid] : 0u;
    s[tid] = v; __syncthreads();
    for (int off = 1; off < 128; off <<= 1) {
        unsigned t = (tid >= off) ? s[tid - off] : 0u;
        __syncthreads();
        s[tid] += t;
        __syncthreads();
    }
    if (tid < NSB) bsum[tid] = s[tid] - v;   // exclusive block offsets
    if (tid == 0) rowptr[NN] = NE;
}

__global__ __launch_bounds__(256) void k_scanC(const uint4* __restrict__ cnt4,
                                               const unsigned* __restrict__ bsum,
                                               uint4* __restrict__ rowptr4,
                                               uint4* __restrict__ cur4) {
    __shared__ unsigned ts[256];
    int tid = threadIdx.x;
    int f = blockIdx.x * 256 + tid;
    uint4 v = {0, 0, 0, 0};
    if (f < NV4) v = cnt4[f];
    unsigned tsum = v.x + v.y + v.z + v.w;
    ts[tid] = tsum; __syncthreads();
    for (int off = 1; off < 256; off <<= 1) {
        unsigned t = (tid >= off) ? ts[tid - off] : 0u;
        __syncthreads();
        ts[tid] += t;
        __syncthreads();
    }
    unsigned ebase = ts[tid] - tsum + bsum[blockIdx.x];  // exclusive prefix
    if (f < NV4) {
        uint4 r;
        r.x = ebase;
        r.y = r.x + v.x;
        r.z = r.y + v.y;
        r.w = r.z + v.z;
        rowptr4[f] = r;
        cur4[f] = r;
    }
}

__global__ __launch_bounds__(256) void k_dinv(const unsigned* __restrict__ rowptr,
                                              float* __restrict__ dinv) {
    int n = blockIdx.x * 256 + threadIdx.x;
    if (n < NN) dinv[n] = rsqrtf((float)(rowptr[n + 1] - rowptr[n]) + 1.0f);
}

__global__ __launch_bounds__(256) void k_fill(const int* __restrict__ src,
                                              const int* __restrict__ dst,
                                              const float* __restrict__ dinv,
                                              unsigned* __restrict__ cur,
                                              int2* __restrict__ edat) {
    int e = blockIdx.x * 256 + threadIdx.x;          // exact NE/256
    int s = src[e], d = dst[e];
    unsigned pos = atomicAdd(&cur[d], 1u);
    edat[pos] = make_int2(s, __float_as_int(dinv[s] * dinv[d]));
}

// ---------- matmul: out[N][32] = X[N][K] @ W[K][32], 128 nodes/block ----------
// thread = 4 nodes x 4 features; x staged transposed in LDS for b128 reads
template <int K>
__global__ __launch_bounds__(256) void k_mm(const float* __restrict__ X,
                                            const float* __restrict__ W,
                                            float* __restrict__ out) {
    __shared__ float Wls[K * HD];
    __shared__ float xT[32][132];                    // +4 pad keeps 16B align, spreads banks
    int tid = threadIdx.x;
    for (int i = tid; i < K * HD; i += 256) Wls[i] = W[i];
    int nb = blockIdx.x * 128;
    int g = tid & 7;        // feature group: j = 4g..4g+3
    int q = tid >> 3;       // node quad:   n = 4q..4q+3
    float acc[4][4] = {};
    for (int kc = 0; kc < K; kc += 32) {
        __syncthreads();
        for (int i = tid; i < 128 * 32; i += 256) {
            int n = i >> 5, kk = i & 31;             // consecutive tid -> consecutive kk (coalesced)
            int node = nb + n;
            xT[kk][n] = (node < NN) ? X[(size_t)node * K + kc + kk] : 0.f;
        }
        __syncthreads();
#pragma unroll
        for (int kk = 0; kk < 32; ++kk) {
            const float4 xv = *(const float4*)&xT[kk][q * 4];
            const float4 wv = *(const float4*)&Wls[(kc + kk) * HD + g * 4];
            acc[0][0] = fmaf(xv.x, wv.x, acc[0][0]);
            acc[0][1] = fmaf(xv.x, wv.y, acc[0][1]);
            acc[0][2] = fmaf(xv.x, wv.z, acc[0][2]);
            acc[0][3] = fmaf(xv.x, wv.w, acc[0][3]);
            acc[1][0] = fmaf(xv.y, wv.x, acc[1][0]);
            acc[1][1] = fmaf(xv.y, wv.y, acc[1][1]);
            acc[1][2] = fmaf(xv.y, wv.z, acc[1][2]);
            acc[1][3] = fmaf(xv.y, wv.w, acc[1][3]);
            acc[2][0] = fmaf(xv.z, wv.x, acc[2][0]);
            acc[2][1] = fmaf(xv.z, wv.y, acc[2][1]);
            acc[2][2] = fmaf(xv.z, wv.z, acc[2][2]);
            acc[2][3] = fmaf(xv.z, wv.w, acc[2][3]);
            acc[3][0] = fmaf(xv.w, wv.x, acc[3][0]);
            acc[3][1] = fmaf(xv.w, wv.y, acc[3][1]);
            acc[3][2] = fmaf(xv.w, wv.z, acc[3][2]);
            acc[3][3] = fmaf(xv.w, wv.w, acc[3][3]);
        }
    }
#pragma unroll
    for (int r = 0; r < 4; ++r) {
        int node = nb + q * 4 + r;
        if (node < NN) {
            float4 o = {acc[r][0], acc[r][1], acc[r][2], acc[r][3]};
            *(float4*)&out[(size_t)node * HD + g * 4] = o;
        }
    }
}

// ---------- CSR gather aggregation; 32 lanes = 32 features per node ----------
// HEAD=false: out = agg + h*self + bias
// HEAD=true : v = agg + h*self + bias, then smu=sum relu(v)*W2, sstd=sum v*Ws
template <bool HEAD>
__global__ __launch_bounds__(256) void k_gather(const int2* __restrict__ edat,
                                                const unsigned* __restrict__ rowptr,
                                                const float* __restrict__ dinv,
                                                const float* __restrict__ h,
                                                const float* __restrict__ bias,
                                                float* __restrict__ out,
                                                const float* __restrict__ W2,
                                                const float* __restrict__ Ws,
                                                float* __restrict__ smu,
                                                float* __restrict__ sstd) {
    int gid = blockIdx.x * 256 + threadIdx.x;        // exact NN*32/256
    int n = gid >> 5, j = gid & 31;
    unsigned s0 = rowptr[n], s1 = rowptr[n + 1];
    float acc = 0.f;
    for (unsigned i = s0; i < s1; ++i) {
        int2 ed = edat[i];                           // broadcast 8B
        acc = fmaf(h[(size_t)ed.x * HD + j], __int_as_float(ed.y), acc);  // coalesced 128B
    }
    float dv = dinv[n];
    float v = acc + h[(size_t)n * HD + j] * dv * dv + bias[j];
    if (!HEAD) {
        out[(size_t)n * HD + j] = v;
    } else {
        float a = fmaxf(v, 0.f) * W2[j];
        float b = v * Ws[j];
#pragma unroll
        for (int off = 16; off > 0; off >>= 1) {
            a += __shfl_xor(a, off, 32);
            b += __shfl_xor(b, off, 32);
        }
        if (j == 0) { smu[n] = a; sstd[n] = b; }
    }
}

// ---------- scalar head gather: 32 lanes split a node's edge list ----------
__global__ __launch_bounds__(256) void k_gscal(const int2* __restrict__ edat,
                                               const unsigned* __restrict__ rowptr,
                                               const float* __restrict__ dinv,
                                               const float* __restrict__ smu,
                                               const float* __restrict__ sstd,
                                               const float* __restrict__ b2,
                                               const float* __restrict__ bs,
                                               float* __restrict__ out) {
    int gid = blockIdx.x * 256 + threadIdx.x;        // exact NN*32/256
    int n = gid >> 5, l = gid & 31;
    unsigned s0 = rowptr[n], s1 = rowptr[n + 1];
    float a = 0.f, b = 0.f;
    for (unsigned i = s0 + l; i < s1; i += 32) {
        int2 ed = edat[i];                           // coalesced 8B
        float w = __int_as_float(ed.y);
        a = fmaf(smu[ed.x], w, a);
        b = fmaf(sstd[ed.x], w, b);
    }
#pragma unroll
    for (int off = 16; off > 0; off >>= 1) {
        a += __shfl_xor(a, off, 32);
        b += __shfl_xor(b, off, 32);
    }
    if (l == 0) {
        float dv = dinv[n];
        float sn = dv * dv;
        out[n]      = a + smu[n]  * sn + b2[0];
        out[NN + n] = b + sstd[n] * sn + bs[0];
    }
}

extern "C" void kernel_launch(void* const* d_in, const int* in_sizes, int n_in,
                              void* d_out, int out_size, void* d_ws, size_t ws_size,
                              hipStream_t stream) {
    const float* x   = (const float*)d_in[0];
    const int*   ei  = (const int*)d_in[1];
    const int*   src = ei;
    const int*   dst = ei + NE;
    const float* W1  = (const float*)d_in[2];
    const float* b1  = (const float*)d_in[3];
    const float* Wh  = (const float*)d_in[4];
    const float* bh  = (const float*)d_in[5];
    const float* W2  = (const float*)d_in[6];
    const float* b2  = (const float*)d_in[7];
    const float* Wsp = (const float*)d_in[8];
    const float* bs  = (const float*)d_in[9];
    float* out = (float*)d_out;

    // workspace layout (4B words), total ~40.4MB:
    // edat[2*NE] | h[NN*32] | hc[NN*32] | rowptr[100004 pad] | cur[NN] | dinv[NN] | smu[NN] | sstd[NN] | bsum[128]
    float*    f      = (float*)d_ws;
    int2*     edat   = (int2*)d_ws;
    float*    h      = f + (size_t)2 * NE;
    float*    hc     = h + (size_t)NN * HD;
    unsigned* rowptr = (unsigned*)(hc + (size_t)NN * HD);
    unsigned* cur    = rowptr + 100004;              // padded so cur is 16B-aligned
    float*    dinv   = (float*)(cur + NN);
    float*    smu    = dinv + NN;
    float*    sstd   = smu + NN;
    unsigned* bsum   = (unsigned*)(sstd + NN);

    // CSR build
    hipMemsetAsync(cur, 0, NN * sizeof(unsigned), stream);
    k_count<<<NE / 256, 256, 0, stream>>>(dst, cur);
    k_scanA<<<NSB, 256, 0, stream>>>((const uint4*)cur, bsum);
    k_scanB<<<1, 128, 0, stream>>>(bsum, rowptr);
    k_scanC<<<NSB, 256, 0, stream>>>((const uint4*)cur, bsum, (uint4*)rowptr, (uint4*)cur);
    k_dinv<<<(NN + 255) / 256, 256, 0, stream>>>(rowptr, dinv);
    k_fill<<<NE / 256, 256, 0, stream>>>(src, dst, dinv, cur, edat);

    // conv1
    k_mm<SD><<<(NN + 127) / 128, 256, 0, stream>>>(x, W1, h);
    k_gather<false><<<NN * HD / 256, 256, 0, stream>>>(edat, rowptr, dinv, h, b1, hc,
                                                       nullptr, nullptr, nullptr, nullptr);
    // conv2 + fused heads
    k_mm<HD><<<(NN + 127) / 128, 256, 0, stream>>>(hc, Wh, h);
    k_gather<true><<<NN * HD / 256, 256, 0, stream>>>(edat, rowptr, dinv, h, bh, nullptr,
                                                      W2, Wsp, smu, sstd);
    // head aggregation -> outputs
    k_gscal<<<NN * HD / 256, 256, 0, stream>>>(edat, rowptr, dinv, smu, sstd, b2, bs, out);
}

// Round 3
// 383.737 us; speedup vs baseline: 2.0339x; 1.4091x over previous
//
#include <hip/hip_runtime.h>

#define NN 100000
#define NE 1600000
#define SD 128
#define HD 32
#define NV4 25000      // NN/4 (exact)
#define NSB 98         // ceil(NV4/256)

// ---------- pass 1: in-degree count + per-edge rank (coalesced) ----------
__global__ __launch_bounds__(256) void k_count(const int* __restrict__ dst,
                                               unsigned* __restrict__ cnt,
                                               unsigned* __restrict__ rank) {
    int e = blockIdx.x * 256 + threadIdx.x;          // exact NE/256
    int d = dst[e];
    rank[e] = atomicAdd(&cnt[d], 1u);
}

// ---------- scan: per-block sums ----------
__global__ __launch_bounds__(256) void k_scanA(const uint4* __restrict__ cnt4,
                                               unsigned* __restrict__ bsum) {
    __shared__ unsigned ts[256];
    int tid = threadIdx.x;
    int f = blockIdx.x * 256 + tid;
    unsigned s = 0;
    if (f < NV4) { uint4 v = cnt4[f]; s = v.x + v.y + v.z + v.w; }
    ts[tid] = s; __syncthreads();
    for (int off = 128; off > 0; off >>= 1) {
        if (tid < off) ts[tid] += ts[tid + off];
        __syncthreads();
    }
    if (tid == 0) bsum[blockIdx.x] = ts[0];
}

__global__ __launch_bounds__(128) void k_scanB(unsigned* __restrict__ bsum,
                                               unsigned* __restrict__ rowptr) {
    __shared__ unsigned s[128];
    int tid = threadIdx.x;
    unsigned v = (tid < NSB) ? bsum[tid] : 0u;
    s[tid] = v; __syncthreads();
    for (int off = 1; off < 128; off <<= 1) {
        unsigned t = (tid >= off) ? s[tid - off] : 0u;
        __syncthreads();
        s[tid] += t;
        __syncthreads();
    }
    if (tid < NSB) bsum[tid] = s[tid] - v;   // exclusive block offsets
    if (tid == 0) rowptr[NN] = NE;
}

// ---------- scan finalize: rowptr + dinv (fused) ----------
__global__ __launch_bounds__(256) void k_scanC(const uint4* __restrict__ cnt4,
                                               const unsigned* __restrict__ bsum,
                                               uint4* __restrict__ rowptr4,
                                               float4* __restrict__ dinv4) {
    __shared__ unsigned ts[256];
    int tid = threadIdx.x;
    int f = blockIdx.x * 256 + tid;
    uint4 v = {0, 0, 0, 0};
    if (f < NV4) v = cnt4[f];
    unsigned tsum = v.x + v.y + v.z + v.w;
    ts[tid] = tsum; __syncthreads();
    for (int off = 1; off < 256; off <<= 1) {
        unsigned t = (tid >= off) ? ts[tid - off] : 0u;
        __syncthreads();
        ts[tid] += t;
        __syncthreads();
    }
    unsigned ebase = ts[tid] - tsum + bsum[blockIdx.x];  // exclusive prefix
    if (f < NV4) {
        uint4 r;
        r.x = ebase;
        r.y = r.x + v.x;
        r.z = r.y + v.y;
        r.w = r.z + v.z;
        rowptr4[f] = r;
        float4 dv;
        dv.x = rsqrtf((float)v.x + 1.0f);
        dv.y = rsqrtf((float)v.y + 1.0f);
        dv.z = rsqrtf((float)v.z + 1.0f);
        dv.w = rsqrtf((float)v.w + 1.0f);
        dinv4[f] = dv;
    }
}

// ---------- pass 2: CSR fill, no atomics ----------
__global__ __launch_bounds__(256) void k_fill(const int* __restrict__ src,
                                              const int* __restrict__ dst,
                                              const unsigned* __restrict__ rank,
                                              const unsigned* __restrict__ rowptr,
                                              unsigned* __restrict__ edat) {
    int e = blockIdx.x * 256 + threadIdx.x;          // exact NE/256
    int d = dst[e];
    edat[rowptr[d] + rank[e]] = (unsigned)src[e];
}

// ---------- hw = (X @ W) * dinv[n]  (N x 128 @ 128 x 32), 128 nodes/block ----------
__global__ __launch_bounds__(256) void k_mm128(const float* __restrict__ X,
                                               const float* __restrict__ W,
                                               const float* __restrict__ dinv,
                                               float* __restrict__ out) {
    __shared__ float Wls[SD * HD];
    __shared__ float xT[32][132];
    int tid = threadIdx.x;
    for (int i = tid; i < SD * HD; i += 256) Wls[i] = W[i];
    int nb = blockIdx.x * 128;
    int g = tid & 7;        // feature group: j = 4g..4g+3
    int q = tid >> 3;       // node quad
    float acc[4][4] = {};
    for (int kc = 0; kc < SD; kc += 32) {
        __syncthreads();
        for (int i = tid; i < 128 * 32; i += 256) {
            int n = i >> 5, kk = i & 31;
            int node = nb + n;
            xT[kk][n] = (node < NN) ? X[(size_t)node * SD + kc + kk] : 0.f;
        }
        __syncthreads();
#pragma unroll
        for (int kk = 0; kk < 32; ++kk) {
            const float4 xv = *(const float4*)&xT[kk][q * 4];
            const float4 wv = *(const float4*)&Wls[(kc + kk) * HD + g * 4];
            acc[0][0] = fmaf(xv.x, wv.x, acc[0][0]);
            acc[0][1] = fmaf(xv.x, wv.y, acc[0][1]);
            acc[0][2] = fmaf(xv.x, wv.z, acc[0][2]);
            acc[0][3] = fmaf(xv.x, wv.w, acc[0][3]);
            acc[1][0] = fmaf(xv.y, wv.x, acc[1][0]);
            acc[1][1] = fmaf(xv.y, wv.y, acc[1][1]);
            acc[1][2] = fmaf(xv.y, wv.z, acc[1][2]);
            acc[1][3] = fmaf(xv.y, wv.w, acc[1][3]);
            acc[2][0] = fmaf(xv.z, wv.x, acc[2][0]);
            acc[2][1] = fmaf(xv.z, wv.y, acc[2][1]);
            acc[2][2] = fmaf(xv.z, wv.z, acc[2][2]);
            acc[2][3] = fmaf(xv.z, wv.w, acc[2][3]);
            acc[3][0] = fmaf(xv.w, wv.x, acc[3][0]);
            acc[3][1] = fmaf(xv.w, wv.y, acc[3][1]);
            acc[3][2] = fmaf(xv.w, wv.z, acc[3][2]);
            acc[3][3] = fmaf(xv.w, wv.w, acc[3][3]);
        }
    }
#pragma unroll
    for (int r = 0; r < 4; ++r) {
        int node = nb + q * 4 + r;
        if (node < NN) {
            float dv = dinv[node];
            float4 o = {acc[r][0] * dv, acc[r][1] * dv, acc[r][2] * dv, acc[r][3] * dv};
            *(float4*)&out[(size_t)node * HD + g * 4] = o;
        }
    }
}

// ---------- gather aggregation; 32 lanes = 32 features per node ----------
// v[j] = dinv[n]*(sum_in hw[s][j] + hw[n][j]) + bias[j]
// MODE 1: out hw2[n][j'] = (sum_j v[j]*Wh[j][j']) * dinv[n]   (fused 32x32 matmul)
// MODE 2: heads: head_w[n] = { dinv*sum relu(v)*W2, dinv*sum v*Ws }
template <int MODE>
__global__ __launch_bounds__(256) void k_gather(const unsigned* __restrict__ edat,
                                                const unsigned* __restrict__ rowptr,
                                                const float* __restrict__ dinv,
                                                const float* __restrict__ hw,
                                                const float* __restrict__ bias,
                                                const float* __restrict__ Wa,
                                                const float* __restrict__ Wb,
                                                float* __restrict__ outw) {
    int gid = blockIdx.x * 256 + threadIdx.x;        // exact NN*32/256
    int n = gid >> 5, j = gid & 31;
    unsigned s0 = rowptr[n], s1 = rowptr[n + 1];
    float acc = 0.f;
    unsigned i = s0;
    for (; i + 1 < s1; i += 2) {                     // 2-deep for ILP
        unsigned ea = edat[i], eb = edat[i + 1];
        float va = hw[(size_t)ea * HD + j];
        float vb = hw[(size_t)eb * HD + j];
        acc += va + vb;
    }
    if (i < s1) acc += hw[(size_t)edat[i] * HD + j];
    float dv = dinv[n];
    float v = dv * (acc + hw[(size_t)n * HD + j]) + bias[j];
    if (MODE == 1) {
        float h2 = 0.f;
#pragma unroll
        for (int jj = 0; jj < 32; ++jj)
            h2 = fmaf(__shfl(v, jj, 32), Wa[jj * HD + j], h2);
        outw[(size_t)n * HD + j] = h2 * dv;
    } else {
        float a = fmaxf(v, 0.f) * Wa[j];
        float b = v * Wb[j];
#pragma unroll
        for (int off = 16; off > 0; off >>= 1) {
            a += __shfl_xor(a, off, 32);
            b += __shfl_xor(b, off, 32);
        }
        if (j == 0) ((float2*)outw)[n] = make_float2(a * dv, b * dv);
    }
}

// ---------- head aggregation -> outputs ----------
__global__ __launch_bounds__(256) void k_gscal(const unsigned* __restrict__ edat,
                                               const unsigned* __restrict__ rowptr,
                                               const float* __restrict__ dinv,
                                               const float2* __restrict__ head_w,
                                               const float* __restrict__ b2,
                                               const float* __restrict__ bs,
                                               float* __restrict__ out) {
    int gid = blockIdx.x * 256 + threadIdx.x;        // exact NN*32/256
    int n = gid >> 5, l = gid & 31;
    unsigned s0 = rowptr[n], s1 = rowptr[n + 1];
    float a = 0.f, b = 0.f;
    for (unsigned i = s0 + l; i < s1; i += 32) {
        float2 w = head_w[edat[i]];                  // 8B random, L2-resident table
        a += w.x; b += w.y;
    }
#pragma unroll
    for (int off = 16; off > 0; off >>= 1) {
        a += __shfl_xor(a, off, 32);
        b += __shfl_xor(b, off, 32);
    }
    if (l == 0) {
        float dv = dinv[n];
        float2 self = head_w[n];
        out[n]      = dv * (a + self.x) + b2[0];
        out[NN + n] = dv * (b + self.y) + bs[0];
    }
}

extern "C" void kernel_launch(void* const* d_in, const int* in_sizes, int n_in,
                              void* d_out, int out_size, void* d_ws, size_t ws_size,
                              hipStream_t stream) {
    const float* x   = (const float*)d_in[0];
    const int*   ei  = (const int*)d_in[1];
    const int*   src = ei;
    const int*   dst = ei + NE;
    const float* W1  = (const float*)d_in[2];
    const float* b1  = (const float*)d_in[3];
    const float* Wh  = (const float*)d_in[4];
    const float* bh  = (const float*)d_in[5];
    const float* W2  = (const float*)d_in[6];
    const float* b2  = (const float*)d_in[7];
    const float* Wsp = (const float*)d_in[8];
    const float* bs  = (const float*)d_in[9];
    float* out = (float*)d_out;

    // workspace (4B words), ~34 MB:
    // edat[1.6M] | hw1[3.2M] | R: rank[1.6M] (dead before hw2) / hw2[3.2M] |
    // rowptr[100004] | cnt[100000] | dinv[100000] | head_w[200000] | bsum[128]
    unsigned* w      = (unsigned*)d_ws;
    unsigned* edat   = w;
    float*    hw1    = (float*)(w + 1600000);
    unsigned* rank   = w + 4800000;                  // aliases hw2's first half
    float*    hw2    = (float*)(w + 4800000);
    unsigned* rowptr = w + 8000000;
    unsigned* cnt    = rowptr + 100004;              // 16B-aligned
    float*    dinv   = (float*)(cnt + 100000);
    float*    headw  = dinv + 100000;                // float2[NN], 8B-aligned
    unsigned* bsum   = (unsigned*)(headw + 200000);

    // CSR build (no-atomic fill via precomputed ranks)
    hipMemsetAsync(cnt, 0, NN * sizeof(unsigned), stream);
    k_count<<<NE / 256, 256, 0, stream>>>(dst, cnt, rank);
    k_scanA<<<NSB, 256, 0, stream>>>((const uint4*)cnt, bsum);
    k_scanB<<<1, 128, 0, stream>>>(bsum, rowptr);
    k_scanC<<<NSB, 256, 0, stream>>>((const uint4*)cnt, bsum, (uint4*)rowptr, (float4*)dinv);
    k_fill<<<NE / 256, 256, 0, stream>>>(src, dst, rank, rowptr, edat);

    // conv1 transform (pre-scaled by dinv)
    k_mm128<<<(NN + 127) / 128, 256, 0, stream>>>(x, W1, dinv, hw1);
    // conv1 aggregate + fused conv2 transform
    k_gather<1><<<NN * HD / 256, 256, 0, stream>>>(edat, rowptr, dinv, hw1, b1, Wh, nullptr, hw2);
    // conv2 aggregate + fused heads
    k_gather<2><<<NN * HD / 256, 256, 0, stream>>>(edat, rowptr, dinv, hw2, bh, W2, Wsp, headw);
    // head aggregation -> outputs
    k_gscal<<<NN * HD / 256, 256, 0, stream>>>(edat, rowptr, dinv, (const float2*)headw, b2, bs, out);
}

// Round 5
// 333.297 us; speedup vs baseline: 2.3416x; 1.1513x over previous
//
#include <hip/hip_runtime.h>

#define NN 100000
#define NE 1600000
#define SD 128
#define HD 32
#define NV4 25000      // NN/4 (exact)
#define NSB 98         // ceil(NV4/256)

// ---------- pass 1: in-degree count + per-edge rank (coalesced) ----------
__global__ __launch_bounds__(256) void k_count(const int* __restrict__ dst,
                                               unsigned* __restrict__ cnt,
                                               unsigned* __restrict__ rank) {
    int e = blockIdx.x * 256 + threadIdx.x;          // exact NE/256
    int d = dst[e];
    rank[e] = atomicAdd(&cnt[d], 1u);
}

// ---------- scan: per-block sums ----------
__global__ __launch_bounds__(256) void k_scanA(const uint4* __restrict__ cnt4,
                                               unsigned* __restrict__ bsum) {
    __shared__ unsigned ts[256];
    int tid = threadIdx.x;
    int f = blockIdx.x * 256 + tid;
    unsigned s = 0;
    if (f < NV4) { uint4 v = cnt4[f]; s = v.x + v.y + v.z + v.w; }
    ts[tid] = s; __syncthreads();
    for (int off = 128; off > 0; off >>= 1) {
        if (tid < off) ts[tid] += ts[tid + off];
        __syncthreads();
    }
    if (tid == 0) bsum[blockIdx.x] = ts[0];
}

__global__ __launch_bounds__(128) void k_scanB(unsigned* __restrict__ bsum,
                                               unsigned* __restrict__ rowptr) {
    __shared__ unsigned s[128];
    int tid = threadIdx.x;
    unsigned v = (tid < NSB) ? bsum[tid] : 0u;
    s[tid] = v; __syncthreads();
    for (int off = 1; off < 128; off <<= 1) {
        unsigned t = (tid >= off) ? s[tid - off] : 0u;
        __syncthreads();
        s[tid] += t;
        __syncthreads();
    }
    if (tid < NSB) bsum[tid] = s[tid] - v;   // exclusive block offsets
    if (tid == 0) rowptr[NN] = NE;
}

// ---------- scan finalize: rowptr + dinv (fused) ----------
__global__ __launch_bounds__(256) void k_scanC(const uint4* __restrict__ cnt4,
                                               const unsigned* __restrict__ bsum,
                                               uint4* __restrict__ rowptr4,
                                               float4* __restrict__ dinv4) {
    __shared__ unsigned ts[256];
    int tid = threadIdx.x;
    int f = blockIdx.x * 256 + tid;
    uint4 v = {0, 0, 0, 0};
    if (f < NV4) v = cnt4[f];
    unsigned tsum = v.x + v.y + v.z + v.w;
    ts[tid] = tsum; __syncthreads();
    for (int off = 1; off < 256; off <<= 1) {
        unsigned t = (tid >= off) ? ts[tid - off] : 0u;
        __syncthreads();
        ts[tid] += t;
        __syncthreads();
    }
    unsigned ebase = ts[tid] - tsum + bsum[blockIdx.x];  // exclusive prefix
    if (f < NV4) {
        uint4 r;
        r.x = ebase;
        r.y = r.x + v.x;
        r.z = r.y + v.y;
        r.w = r.z + v.z;
        rowptr4[f] = r;
        float4 dv;
        dv.x = rsqrtf((float)v.x + 1.0f);
        dv.y = rsqrtf((float)v.y + 1.0f);
        dv.z = rsqrtf((float)v.z + 1.0f);
        dv.w = rsqrtf((float)v.w + 1.0f);
        dinv4[f] = dv;
    }
}

// ---------- pass 2: CSR fill, no atomics ----------
__global__ __launch_bounds__(256) void k_fill(const int* __restrict__ src,
                                              const int* __restrict__ dst,
                                              const unsigned* __restrict__ rank,
                                              const unsigned* __restrict__ rowptr,
                                              unsigned* __restrict__ edat) {
    int e = blockIdx.x * 256 + threadIdx.x;          // exact NE/256
    int d = dst[e];
    edat[rowptr[d] + rank[e]] = (unsigned)src[e];
}

// ---------- hw = (X @ W1) * dinv[n] : 256 nodes/block, thread = 8n x 4f ----------
__global__ __launch_bounds__(256) void k_mm128(const float* __restrict__ X,
                                               const float* __restrict__ W,
                                               const float* __restrict__ dinv,
                                               float* __restrict__ out) {
    __shared__ float Wls[SD * HD];       // 16 KB
    __shared__ float xT[32][260];        // 33.3 KB; rows 16B-aligned, reads 2-way (free)
    int tid = threadIdx.x;
    {   // stage W: 4096 floats, float4
        const float4* W4 = (const float4*)W;
        float4* Wl4 = (float4*)Wls;
        for (int i = tid; i < SD * HD / 4; i += 256) Wl4[i] = W4[i];
    }
    int nb = blockIdx.x * 256;
    int g = tid & 7;        // feature quad: j = 4g..4g+3
    int q = tid >> 3;       // node octet:   n = 8q..8q+7
    float acc[8][4] = {};
    for (int kc = 0; kc < SD; kc += 32) {
        __syncthreads();
        // stage 256 nodes x 32 k (transposed): thread loads 8 float4 (coalesced 128B/node)
        for (int i = tid; i < 256 * 8; i += 256) {
            int n = i >> 3, k4 = i & 7;
            int node = nb + n;
            float4 v = (node < NN) ? *(const float4*)&X[(size_t)node * SD + kc + k4 * 4]
                                   : make_float4(0.f, 0.f, 0.f, 0.f);
            xT[k4 * 4 + 0][n] = v.x;
            xT[k4 * 4 + 1][n] = v.y;
            xT[k4 * 4 + 2][n] = v.z;
            xT[k4 * 4 + 3][n] = v.w;
        }
        __syncthreads();
#pragma unroll
        for (int kk = 0; kk < 32; ++kk) {
            const float4 xa = *(const float4*)&xT[kk][q * 8];
            const float4 xb = *(const float4*)&xT[kk][q * 8 + 4];
            const float4 wv = *(const float4*)&Wls[(kc + kk) * HD + g * 4];
            acc[0][0] = fmaf(xa.x, wv.x, acc[0][0]);
            acc[0][1] = fmaf(xa.x, wv.y, acc[0][1]);
            acc[0][2] = fmaf(xa.x, wv.z, acc[0][2]);
            acc[0][3] = fmaf(xa.x, wv.w, acc[0][3]);
            acc[1][0] = fmaf(xa.y, wv.x, acc[1][0]);
            acc[1][1] = fmaf(xa.y, wv.y, acc[1][1]);
            acc[1][2] = fmaf(xa.y, wv.z, acc[1][2]);
            acc[1][3] = fmaf(xa.y, wv.w, acc[1][3]);
            acc[2][0] = fmaf(xa.z, wv.x, acc[2][0]);
            acc[2][1] = fmaf(xa.z, wv.y, acc[2][1]);
            acc[2][2] = fmaf(xa.z, wv.z, acc[2][2]);
            acc[2][3] = fmaf(xa.z, wv.w, acc[2][3]);
            acc[3][0] = fmaf(xa.w, wv.x, acc[3][0]);
            acc[3][1] = fmaf(xa.w, wv.y, acc[3][1]);
            acc[3][2] = fmaf(xa.w, wv.z, acc[3][2]);
            acc[3][3] = fmaf(xa.w, wv.w, acc[3][3]);
            acc[4][0] = fmaf(xb.x, wv.x, acc[4][0]);
            acc[4][1] = fmaf(xb.x, wv.y, acc[4][1]);
            acc[4][2] = fmaf(xb.x, wv.z, acc[4][2]);
            acc[4][3] = fmaf(xb.x, wv.w, acc[4][3]);
            acc[5][0] = fmaf(xb.y, wv.x, acc[5][0]);
            acc[5][1] = fmaf(xb.y, wv.y, acc[5][1]);
            acc[5][2] = fmaf(xb.y, wv.z, acc[5][2]);
            acc[5][3] = fmaf(xb.y, wv.w, acc[5][3]);
            acc[6][0] = fmaf(xb.z, wv.x, acc[6][0]);
            acc[6][1] = fmaf(xb.z, wv.y, acc[6][1]);
            acc[6][2] = fmaf(xb.z, wv.z, acc[6][2]);
            acc[6][3] = fmaf(xb.z, wv.w, acc[6][3]);
            acc[7][0] = fmaf(xb.w, wv.x, acc[7][0]);
            acc[7][1] = fmaf(xb.w, wv.y, acc[7][1]);
            acc[7][2] = fmaf(xb.w, wv.z, acc[7][2]);
            acc[7][3] = fmaf(xb.w, wv.w, acc[7][3]);
        }
    }
#pragma unroll
    for (int r = 0; r < 8; ++r) {
        int node = nb + q * 8 + r;
        if (node < NN) {
            float dv = dinv[node];
            float4 o = {acc[r][0] * dv, acc[r][1] * dv, acc[r][2] * dv, acc[r][3] * dv};
            *(float4*)&out[(size_t)node * HD + g * 4] = o;
        }
    }
}

// ---------- gather aggregation; 32 lanes = 32 features per node ----------
// v[j] = dinv[n]*(sum_in hw[s][j] + hw[n][j]) + bias[j]
// MODE 1: hw2[n][j'] = (sum_j v[j]*Wa[j][j']) * dinv[n]   (fused 32x32 matmul)
// MODE 2: heads: outw[n] = { dinv*sum relu(v)*Wa, dinv*sum v*Wb }
template <int MODE>
__global__ __launch_bounds__(256) void k_gather(const unsigned* __restrict__ edat,
                                                const unsigned* __restrict__ rowptr,
                                                const float* __restrict__ dinv,
                                                const float* __restrict__ hw,
                                                const float* __restrict__ bias,
                                                const float* __restrict__ Wa,
                                                const float* __restrict__ Wb,
                                                float* __restrict__ outw) {
    int gid = blockIdx.x * 256 + threadIdx.x;        // exact NN*32/256
    int n = gid >> 5, j = gid & 31;
    unsigned s0 = rowptr[n], s1 = rowptr[n + 1];
    float acc = 0.f;
    unsigned i = s0;
    for (; i + 4 <= s1; i += 4) {                    // 4-deep: 4 row-loads in flight
        unsigned e0 = edat[i], e1 = edat[i + 1], e2 = edat[i + 2], e3 = edat[i + 3];
        float v0 = hw[(size_t)e0 * HD + j];
        float v1 = hw[(size_t)e1 * HD + j];
        float v2 = hw[(size_t)e2 * HD + j];
        float v3 = hw[(size_t)e3 * HD + j];
        acc += (v0 + v1) + (v2 + v3);
    }
    for (; i < s1; ++i) acc += hw[(size_t)edat[i] * HD + j];
    float dv = dinv[n];
    float v = dv * (acc + hw[(size_t)n * HD + j]) + bias[j];
    if (MODE == 1) {
        float h2 = 0.f;
#pragma unroll
        for (int jj = 0; jj < 32; ++jj)
            h2 = fmaf(__shfl(v, jj, 32), Wa[jj * HD + j], h2);
        outw[(size_t)n * HD + j] = h2 * dv;
    } else {
        float a = fmaxf(v, 0.f) * Wa[j];
        float b = v * Wb[j];
#pragma unroll
        for (int off = 16; off > 0; off >>= 1) {
            a += __shfl_xor(a, off, 32);
            b += __shfl_xor(b, off, 32);
        }
        if (j == 0) ((float2*)outw)[n] = make_float2(a * dv, b * dv);
    }
}

// ---------- head aggregation -> outputs ----------
__global__ __launch_bounds__(256) void k_gscal(const unsigned* __restrict__ edat,
                                               const unsigned* __restrict__ rowptr,
                                               const float* __restrict__ dinv,
                                               const float2* __restrict__ head_w,
                                               const float* __restrict__ b2,
                                               const float* __restrict__ bs,
                                               float* __restrict__ out) {
    int gid = blockIdx.x * 256 + threadIdx.x;        // exact NN*32/256
    int n = gid >> 5, l = gid & 31;
    unsigned s0 = rowptr[n], s1 = rowptr[n + 1];
    float a = 0.f, b = 0.f;
    for (unsigned i = s0 + l; i < s1; i += 32) {
        float2 w = head_w[edat[i]];                  // 8B random, L2-resident table
        a += w.x; b += w.y;
    }
#pragma unroll
    for (int off = 16; off > 0; off >>= 1) {
        a += __shfl_xor(a, off, 32);
        b += __shfl_xor(b, off, 32);
    }
    if (l == 0) {
        float dv = dinv[n];
        float2 self = head_w[n];
        out[n]      = dv * (a + self.x) + b2[0];
        out[NN + n] = dv * (b + self.y) + bs[0];
    }
}

extern "C" void kernel_launch(void* const* d_in, const int* in_sizes, int n_in,
                              void* d_out, int out_size, void* d_ws, size_t ws_size,
                              hipStream_t stream) {
    const float* x   = (const float*)d_in[0];
    const int*   ei  = (const int*)d_in[1];
    const int*   src = ei;
    const int*   dst = ei + NE;
    const float* W1  = (const float*)d_in[2];
    const float* b1  = (const float*)d_in[3];
    const float* Wh  = (const float*)d_in[4];
    const float* bh  = (const float*)d_in[5];
    const float* W2  = (const float*)d_in[6];
    const float* b2  = (const float*)d_in[7];
    const float* Wsp = (const float*)d_in[8];
    const float* bs  = (const float*)d_in[9];
    float* out = (float*)d_out;

    // workspace (4B words), ~34 MB:
    // edat[1.6M] | hw1[3.2M] | R: rank[1.6M] (dead before hw2) / hw2[3.2M] |
    // rowptr[100004] | cnt[100000] | dinv[100000] | head_w[200000] | bsum[128]
    unsigned* w      = (unsigned*)d_ws;
    unsigned* edat   = w;
    float*    hw1    = (float*)(w + 1600000);
    unsigned* rank   = w + 4800000;                  // aliases hw2's first half
    float*    hw2    = (float*)(w + 4800000);
    unsigned* rowptr = w + 8000000;
    unsigned* cnt    = rowptr + 100004;              // 16B-aligned
    float*    dinv   = (float*)(cnt + 100000);
    float*    headw  = dinv + 100000;                // float2[NN]
    unsigned* bsum   = (unsigned*)(headw + 200000);

    // CSR build (no-atomic fill via precomputed ranks)
    hipMemsetAsync(cnt, 0, NN * sizeof(unsigned), stream);
    k_count<<<NE / 256, 256, 0, stream>>>(dst, cnt, rank);
    k_scanA<<<NSB, 256, 0, stream>>>((const uint4*)cnt, bsum);
    k_scanB<<<1, 128, 0, stream>>>(bsum, rowptr);
    k_scanC<<<NSB, 256, 0, stream>>>((const uint4*)cnt, bsum, (uint4*)rowptr, (float4*)dinv);
    k_fill<<<NE / 256, 256, 0, stream>>>(src, dst, rank, rowptr, edat);

    // conv1 transform (pre-scaled by dinv)
    k_mm128<<<(NN + 255) / 256, 256, 0, stream>>>(x, W1, dinv, hw1);
    // conv1 aggregate + fused conv2 transform
    k_gather<1><<<NN * HD / 256, 256, 0, stream>>>(edat, rowptr, dinv, hw1, b1, Wh, nullptr, hw2);
    // conv2 aggregate + fused heads
    k_gather<2><<<NN * HD / 256, 256, 0, stream>>>(edat, rowptr, dinv, hw2, bh, W2, Wsp, headw);
    // head aggregation -> outputs
    k_gscal<<<NN * HD / 256, 256, 0, stream>>>(edat, rowptr, dinv, (const float2*)headw, b2, bs, out);
}